// Round 7
// baseline (28385.138 us; speedup 1.0000x reference)
//
#include <hip/hip_runtime.h>
#include <hip/hip_bf16.h>

// Problem constants
// B=32, L=128, C=20, TOKEN_EMBED=300, CHAR_EMBED=50, NUM_FILTERS=200, KERNEL=3
// HID=256, LABELS=8, NS=6, D0=500, D1=512, BL=4096

typedef float floatx2 __attribute__((ext_vector_type(2)));
typedef short bf16x8 __attribute__((ext_vector_type(8)));
typedef float f32x4  __attribute__((ext_vector_type(4)));

__device__ __forceinline__ unsigned short f2bf(float x) {
    unsigned u = __float_as_uint(x);
    unsigned r = (u + 0x7fffu + ((u >> 16) & 1u)) >> 16;
    return (unsigned short)r;
}

// ---------------------------------------------------------------------------
// Prep: pack w_hh (both layers) to fp8 e4m3 as uint2 per (dir,k2,t):
//   .x = packed (i,f,g,o) for k=2*k2, .y = for k=2*k2+1.
// Also transpose crf_w / conv_w; zero d_out.
// ---------------------------------------------------------------------------
__global__ void prep(const float* __restrict__ wh0, const float* __restrict__ wh1,
                     const float* __restrict__ crf_w, const float* __restrict__ conv_w,
                     uint2* __restrict__ Wp0, uint2* __restrict__ Wp1,
                     float* __restrict__ crfBT, float* __restrict__ convWT,
                     float* __restrict__ outp)
{
    int idx = blockIdx.x * 256 + threadIdx.x;
    if (idx == 0) outp[0] = 0.f;
    const int NWP = 2 * 2 * 128 * 256;   // layer, dir, k2, t = 131072
    if (idx < NWP) {
        int layer = idx >> 16;
        int r     = idx & 65535;
        int dir   = r >> 15;
        int q     = r & 32767;
        int k2    = q >> 8;              // 0..127
        int t     = q & 255;
        const float* w = (layer ? wh1 : wh0) + dir * 1024 * 256;
        uint2 v;
        {
            int k = 2 * k2;
            float wi = w[(t      ) * 256 + k];
            float wf = w[(256 + t) * 256 + k];
            float wg = w[(512 + t) * 256 + k];
            float wo = w[(768 + t) * 256 + k];
            int u = __builtin_amdgcn_cvt_pk_fp8_f32(wi, wf, 0, false);
            u     = __builtin_amdgcn_cvt_pk_fp8_f32(wg, wo, u, true);
            v.x = (unsigned)u;
        }
        {
            int k = 2 * k2 + 1;
            float wi = w[(t      ) * 256 + k];
            float wf = w[(256 + t) * 256 + k];
            float wg = w[(512 + t) * 256 + k];
            float wo = w[(768 + t) * 256 + k];
            int u = __builtin_amdgcn_cvt_pk_fp8_f32(wi, wf, 0, false);
            u     = __builtin_amdgcn_cvt_pk_fp8_f32(wg, wo, u, true);
            v.y = (unsigned)u;
        }
        ((layer ? Wp1 : Wp0))[(size_t)dir * 32768 + k2 * 256 + t] = v;
        return;
    }
    idx -= NWP;
    if (idx < 48 * 512) {
        int jj = idx >> 9, d = idx & 511;
        int kL = jj / 6, n = jj % 6;
        crfBT[idx] = crf_w[(kL * 512 + d) * 6 + n];
        return;
    }
    idx -= 48 * 512;
    if (idx < 30000) {
        int f = idx % 200, ek = idx / 200;
        int e = ek / 3, kk = ek % 3;
        convWT[idx] = conv_w[(f * 50 + e) * 3 + kk];
        return;
    }
}

// ---------------------------------------------------------------------------
// Embeddings + char conv + concat -> inp (4096 x 500)
// ---------------------------------------------------------------------------
__global__ __launch_bounds__(256) void embed_conv(
    const int* __restrict__ iv, const int* __restrict__ ov, const int* __restrict__ ch,
    const float* __restrict__ emb, const float* __restrict__ ooev, const float* __restrict__ ctab,
    const float* __restrict__ convWT, const float* __restrict__ convB,
    float* __restrict__ inp)
{
    const int bl = blockIdx.x;
    const int tid = threadIdx.x;
    __shared__ float sx[50 * 20];
    const int ivv = iv[bl];
    const int ovv = ov[bl];
    const float mo = (ovv != 0) ? 1.f : 0.f;
    for (int e = tid; e < 300; e += 256)
        inp[bl * 500 + e] = emb[(size_t)ivv * 300 + e] + mo * ooev[(size_t)ovv * 300 + e];
    for (int i = tid; i < 1000; i += 256) {
        int cI = i / 50, e = i % 50;
        int id = ch[bl * 20 + cI];
        sx[e * 20 + cI] = id ? ctab[id * 50 + e] : 0.f;
    }
    __syncthreads();
    if (tid < 200) {
        float acc[22];
        float bz = convB[tid];
        #pragma unroll
        for (int o = 0; o < 22; ++o) acc[o] = bz;
        for (int e = 0; e < 50; ++e) {
            float xr[20];
            #pragma unroll
            for (int q = 0; q < 5; ++q) {
                float4 v = *(const float4*)&sx[e * 20 + q * 4];
                xr[q * 4 + 0] = v.x; xr[q * 4 + 1] = v.y;
                xr[q * 4 + 2] = v.z; xr[q * 4 + 3] = v.w;
            }
            float w0 = convWT[(e * 3 + 0) * 200 + tid];
            float w1 = convWT[(e * 3 + 1) * 200 + tid];
            float w2 = convWT[(e * 3 + 2) * 200 + tid];
            #pragma unroll
            for (int o = 0; o < 22; ++o) {
                float s = acc[o];
                if (o >= 2)            s = fmaf(xr[o - 2], w0, s);
                if (o >= 1 && o <= 20) s = fmaf(xr[o - 1], w1, s);
                if (o <= 19)           s = fmaf(xr[o],     w2, s);
                acc[o] = s;
            }
        }
        float mx = acc[0];
        #pragma unroll
        for (int o = 1; o < 22; ++o) mx = fmaxf(mx, acc[o]);
        inp[bl * 500 + 300 + tid] = 1.f / (1.f + expf(-mx));
    }
}

// ---------------------------------------------------------------------------
// MFMA bf16 GEMM: C[m][n] = bias[n] + sum_k A[m][k]*Bm[n][k]
// 128x128 tile, 256 thr = 4 waves; wave w owns rows [w*32, w*32+32).
// LDS frag-major [ko][row][8] bf16 so all b128 reads are conflict-free.
// Layouts (verified, learn_hip m89/m120): A/B frag [m|n]=lane&15, k=quad*8+j;
// C/D: col=lane&15, row=quad*4+reg.
// Requires M%128==0, N%128==0 (true: 4096, 2048); K arbitrary (zero-padded).
// ---------------------------------------------------------------------------
__global__ __launch_bounds__(256) void gemm_mfma(
    const float* __restrict__ A, const float* __restrict__ Bm,
    const float* __restrict__ bias, float* __restrict__ C,
    int M, int N, int K)
{
    __shared__ unsigned short As[4][128][8];
    __shared__ unsigned short Bs[4][128][8];
    const int tid  = threadIdx.x;
    const int wave = tid >> 6, lane = tid & 63;
    const int quad = lane >> 4, lr = lane & 15;
    const int m0 = blockIdx.y * 128, n0 = blockIdx.x * 128;

    f32x4 acc[2][8];
    #pragma unroll
    for (int mt = 0; mt < 2; ++mt)
        #pragma unroll
        for (int nt = 0; nt < 8; ++nt) acc[mt][nt] = (f32x4){0.f, 0.f, 0.f, 0.f};

    const int ktiles = (K + 31) >> 5;
    for (int kt = 0; kt < ktiles; ++kt) {
        // stage 128x32 of A and Bm as bf16: vid = tid + i*256 over 1024
        // row = vid>>3, kq = vid&7 -> k = kt*32 + kq*4 + j
        #pragma unroll
        for (int i = 0; i < 4; ++i) {
            int vid = tid + i * 256;
            int row = vid >> 3, kq = vid & 7;
            int kb  = kt * 32 + kq * 4;
            unsigned short ta[4], tb[4];
            const float* pa = A  + (size_t)(m0 + row) * K + kb;
            const float* pb = Bm + (size_t)(n0 + row) * K + kb;
            #pragma unroll
            for (int j = 0; j < 4; ++j) {
                ta[j] = (kb + j < K) ? f2bf(pa[j]) : (unsigned short)0;
                tb[j] = (kb + j < K) ? f2bf(pb[j]) : (unsigned short)0;
            }
            int ko = kq >> 1, jo = (kq & 1) * 4;
            *(ushort4*)&As[ko][row][jo] = make_ushort4(ta[0], ta[1], ta[2], ta[3]);
            *(ushort4*)&Bs[ko][row][jo] = make_ushort4(tb[0], tb[1], tb[2], tb[3]);
        }
        __syncthreads();
        bf16x8 bfr[8];
        #pragma unroll
        for (int nt = 0; nt < 8; ++nt)
            bfr[nt] = *(const bf16x8*)&Bs[quad][nt * 16 + lr][0];
        #pragma unroll
        for (int mt = 0; mt < 2; ++mt) {
            bf16x8 afr = *(const bf16x8*)&As[quad][wave * 32 + mt * 16 + lr][0];
            #pragma unroll
            for (int nt = 0; nt < 8; ++nt)
                acc[mt][nt] = __builtin_amdgcn_mfma_f32_16x16x32_bf16(
                    afr, bfr[nt], acc[mt][nt], 0, 0, 0);
        }
        __syncthreads();
    }
    #pragma unroll
    for (int mt = 0; mt < 2; ++mt)
        #pragma unroll
        for (int r = 0; r < 4; ++r) {
            int m = m0 + wave * 32 + mt * 16 + quad * 4 + r;
            #pragma unroll
            for (int nt = 0; nt < 8; ++nt) {
                int n = n0 + nt * 16 + lr;
                C[(size_t)m * N + n] = acc[mt][nt][r] + bias[n];
            }
        }
}

// ---------------------------------------------------------------------------
// fp32 GEMM (kept for the small emission GEMM, N=48)
// ---------------------------------------------------------------------------
__global__ __launch_bounds__(256) void gemm_bt(
    const float* __restrict__ A, const float* __restrict__ Bm,
    const float* __restrict__ bias, float* __restrict__ C,
    int M, int N, int K)
{
    __shared__ float At[16 * 128];
    __shared__ float Bt[16 * 128];
    const int tid = threadIdx.x;
    const int tx = tid & 15, ty = tid >> 4;
    const int m0 = blockIdx.y * 128, n0 = blockIdx.x * 128;
    float acc[2][2][4][4];
    #pragma unroll
    for (int a = 0; a < 2; ++a)
        #pragma unroll
        for (int b = 0; b < 2; ++b)
            #pragma unroll
            for (int i = 0; i < 4; ++i)
                #pragma unroll
                for (int j = 0; j < 4; ++j) acc[a][b][i][j] = 0.f;

    const int lr = tid >> 2;
    const int lc = (tid & 3) << 2;
    const int ktiles = (K + 15) >> 4;
    for (int kt = 0; kt < ktiles; ++kt) {
        const int k0 = kt << 4;
        #pragma unroll
        for (int half = 0; half < 2; ++half) {
            int r = lr + half * 64;
            int gk = k0 + lc;
            {
                int gm = m0 + r;
                float4 v = make_float4(0.f, 0.f, 0.f, 0.f);
                if (gm < M) {
                    const float* p = A + (size_t)gm * K + gk;
                    if (gk + 3 < K) v = *(const float4*)p;
                    else {
                        if (gk + 0 < K) v.x = p[0];
                        if (gk + 1 < K) v.y = p[1];
                        if (gk + 2 < K) v.z = p[2];
                        if (gk + 3 < K) v.w = p[3];
                    }
                }
                At[(lc + 0) * 128 + r] = v.x; At[(lc + 1) * 128 + r] = v.y;
                At[(lc + 2) * 128 + r] = v.z; At[(lc + 3) * 128 + r] = v.w;
            }
            {
                int gn = n0 + r;
                float4 v = make_float4(0.f, 0.f, 0.f, 0.f);
                if (gn < N) {
                    const float* p = Bm + (size_t)gn * K + gk;
                    if (gk + 3 < K) v = *(const float4*)p;
                    else {
                        if (gk + 0 < K) v.x = p[0];
                        if (gk + 1 < K) v.y = p[1];
                        if (gk + 2 < K) v.z = p[2];
                        if (gk + 3 < K) v.w = p[3];
                    }
                }
                Bt[(lc + 0) * 128 + r] = v.x; Bt[(lc + 1) * 128 + r] = v.y;
                Bt[(lc + 2) * 128 + r] = v.z; Bt[(lc + 3) * 128 + r] = v.w;
            }
        }
        __syncthreads();
        #pragma unroll
        for (int k = 0; k < 16; ++k) {
            float4 a0 = *(const float4*)&At[k * 128 + (ty << 2)];
            float4 a1 = *(const float4*)&At[k * 128 + 64 + (ty << 2)];
            float4 b0 = *(const float4*)&Bt[k * 128 + (tx << 2)];
            float4 b1 = *(const float4*)&Bt[k * 128 + 64 + (tx << 2)];
            float am[2][4] = {{a0.x, a0.y, a0.z, a0.w}, {a1.x, a1.y, a1.z, a1.w}};
            float bn[2][4] = {{b0.x, b0.y, b0.z, b0.w}, {b1.x, b1.y, b1.z, b1.w}};
            #pragma unroll
            for (int qa = 0; qa < 2; ++qa)
                #pragma unroll
                for (int qb = 0; qb < 2; ++qb)
                    #pragma unroll
                    for (int i = 0; i < 4; ++i)
                        #pragma unroll
                        for (int j = 0; j < 4; ++j)
                            acc[qa][qb][i][j] = fmaf(am[qa][i], bn[qb][j], acc[qa][qb][i][j]);
        }
        __syncthreads();
    }
    #pragma unroll
    for (int qa = 0; qa < 2; ++qa)
        #pragma unroll
        for (int i = 0; i < 4; ++i) {
            int m = m0 + qa * 64 + (ty << 2) + i;
            if (m >= M) continue;
            #pragma unroll
            for (int qb = 0; qb < 2; ++qb)
                #pragma unroll
                for (int j = 0; j < 4; ++j) {
                    int n = n0 + qb * 64 + (tx << 2) + j;
                    if (n < N) C[(size_t)m * N + n] = acc[qa][qb][i][j] + bias[n];
                }
        }
}

// ---------------------------------------------------------------------------
// LSTM recurrence v7: fp8 weights fully REGISTER-STATIONARY.
// 64 blocks = (b, dir); 256 threads = t; __launch_bounds__(256,1) -> 1
// wave/SIMD -> 512-VGPR cap. wreg[128] uint2 = 256 VGPR + ~40 working: fits
// (m08: no spill through 450). R4/R5 spilled because their caps (128/256)
// were smaller than the array itself. All wreg indices compile-time constant.
// ---------------------------------------------------------------------------
__global__ __launch_bounds__(256, 1) void lstm_rec(
    const float* __restrict__ xs, const uint2* __restrict__ Wp,
    const float* __restrict__ mask, float* __restrict__ out)
{
    const int t   = threadIdx.x;
    const int b   = blockIdx.x >> 1;
    const int dir = blockIdx.x & 1;
    __shared__ float hs[256];
    float h = 0.f, c = 0.f;
    hs[t] = 0.f;
    __syncthreads();
    const uint2* wp = Wp + (size_t)dir * 32768 + t;
    uint2 wreg[128];
    #pragma unroll
    for (int j = 0; j < 128; ++j) wreg[j] = wp[j * 256];

    for (int s = 0; s < 128; ++s) {
        const int l = dir ? (127 - s) : s;
        const float* gx = xs + ((size_t)(b * 128 + l) * 2048 + dir * 1024 + t);
        float ai = gx[0], af = gx[256], ag = gx[512], ao = gx[768];
        const float m = mask[b * 128 + l];
        #pragma unroll
        for (int k2 = 0; k2 < 128; ++k2) {
            uint2 w = wreg[k2];
            float2 hv = *(const float2*)&hs[k2 * 2];     // wave-uniform bcast
            floatx2 lo0 = __builtin_amdgcn_cvt_pk_f32_fp8((int)w.x, false); // (i,f) k even
            floatx2 hi0 = __builtin_amdgcn_cvt_pk_f32_fp8((int)w.x, true);  // (g,o)
            floatx2 lo1 = __builtin_amdgcn_cvt_pk_f32_fp8((int)w.y, false); // k odd
            floatx2 hi1 = __builtin_amdgcn_cvt_pk_f32_fp8((int)w.y, true);
            ai = fmaf(hv.x, lo0.x, ai); af = fmaf(hv.x, lo0.y, af);
            ag = fmaf(hv.x, hi0.x, ag); ao = fmaf(hv.x, hi0.y, ao);
            ai = fmaf(hv.y, lo1.x, ai); af = fmaf(hv.y, lo1.y, af);
            ag = fmaf(hv.y, hi1.x, ag); ao = fmaf(hv.y, hi1.y, ao);
        }
        float ig = 1.f / (1.f + __expf(-ai));
        float fg = 1.f / (1.f + __expf(-af));
        float gg = tanhf(ag);
        float og = 1.f / (1.f + __expf(-ao));
        float cn = fmaf(fg, c, ig * gg);
        float hn = og * tanhf(cn);
        h = m * hn + (1.f - m) * h;
        c = m * cn + (1.f - m) * c;
        __syncthreads();            // all lanes done reading hs of prev step
        hs[t] = h;
        out[(size_t)(b * 128 + l) * 512 + dir * 256 + t] = h;
        __syncthreads();            // new hs visible before next step's reads
    }
}

// ---------------------------------------------------------------------------
// CRF loss: 8 blocks (one per label k), 192 threads = (b in 0..31, j in 0..5)
// ---------------------------------------------------------------------------
__global__ __launch_bounds__(192) void crf_loss(
    const float* __restrict__ em, const float* __restrict__ trans,
    const int* __restrict__ target, const float* __restrict__ mask,
    float* __restrict__ outp)
{
    const int k = blockIdx.x;
    const int tid = threadIdx.x;
    const int b = tid & 31;
    const int j = tid >> 5;
    __shared__ float T[36];
    __shared__ float As[32][6];
    __shared__ float red[192];
    if (tid < 36) T[tid] = trans[k * 36 + tid];
    __syncthreads();
    const int* tg = target + (k * 32 + b) * 128;
    float sc = 0.f;
    for (int l = j; l < 128; l += 6) {
        int y = tg[l];
        float m = mask[b * 128 + l];
        sc += m * em[(b * 128 + l) * 48 + k * 6 + y];
        if (l > 0) sc += m * T[tg[l - 1] * 6 + y];
    }
    red[tid] = sc;
    float a = em[(b * 128) * 48 + k * 6 + j];
    As[b][j] = a;
    __syncthreads();
    for (int l = 1; l < 128; ++l) {
        float e = em[(b * 128 + l) * 48 + k * 6 + j];
        float v0 = As[b][0] + T[0 * 6 + j];
        float v1 = As[b][1] + T[1 * 6 + j];
        float v2 = As[b][2] + T[2 * 6 + j];
        float v3 = As[b][3] + T[3 * 6 + j];
        float v4 = As[b][4] + T[4 * 6 + j];
        float v5 = As[b][5] + T[5 * 6 + j];
        float mx = fmaxf(fmaxf(fmaxf(v0, v1), fmaxf(v2, v3)), fmaxf(v4, v5));
        float ssum = expf(v0 - mx) + expf(v1 - mx) + expf(v2 - mx)
                   + expf(v3 - mx) + expf(v4 - mx) + expf(v5 - mx);
        float na = mx + logf(ssum) + e;
        float m = mask[b * 128 + l];
        a = m * na + (1.f - m) * a;
        __syncthreads();
        As[b][j] = a;
        __syncthreads();
    }
    if (j == 0) {
        float v0 = As[b][0], v1 = As[b][1], v2 = As[b][2];
        float v3 = As[b][3], v4 = As[b][4], v5 = As[b][5];
        float mx = fmaxf(fmaxf(fmaxf(v0, v1), fmaxf(v2, v3)), fmaxf(v4, v5));
        float ssum = expf(v0 - mx) + expf(v1 - mx) + expf(v2 - mx)
                   + expf(v3 - mx) + expf(v4 - mx) + expf(v5 - mx);
        float logZ = mx + logf(ssum);
        float scb = red[b] + red[b + 32] + red[b + 64] + red[b + 96] + red[b + 128] + red[b + 160];
        red[b] = logZ - scb;
    }
    __syncthreads();
    if (tid == 0) {
        float tot = 0.f;
        for (int bb = 0; bb < 32; ++bb) tot += red[bb];
        atomicAdd(outp, tot * (1.f / 32.f));
    }
}

// ---------------------------------------------------------------------------
extern "C" void kernel_launch(void* const* d_in, const int* in_sizes, int n_in,
                              void* d_out, int out_size, void* d_ws, size_t ws_size,
                              hipStream_t stream)
{
    const int*   iv    = (const int*)d_in[0];
    const int*   ov    = (const int*)d_in[1];
    const int*   ch    = (const int*)d_in[2];
    const int*   tgt   = (const int*)d_in[3];
    const float* mask  = (const float*)d_in[4];
    const float* emb   = (const float*)d_in[5];
    const float* ooevT = (const float*)d_in[6];
    const float* ctab  = (const float*)d_in[7];
    const float* convW = (const float*)d_in[8];
    const float* convB = (const float*)d_in[9];
    const float* wih0  = (const float*)d_in[10];
    const float* whh0  = (const float*)d_in[11];
    const float* b0    = (const float*)d_in[12];
    const float* wih1  = (const float*)d_in[13];
    const float* whh1  = (const float*)d_in[14];
    const float* b1    = (const float*)d_in[15];
    const float* crfW  = (const float*)d_in[16];
    const float* crfB  = (const float*)d_in[17];
    const float* crfT  = (const float*)d_in[18];
    float* outp = (float*)d_out;

    char* ws = (char*)d_ws;
    size_t off = 0;
    auto alloc = [&](size_t bytes) {
        void* p = ws + off;
        off = (off + bytes + 255) & ~(size_t)255;
        return p;
    };
    float* inp    = (float*)alloc((size_t)4096 * 500 * 4);
    float* xs     = (float*)alloc((size_t)4096 * 2048 * 4);
    float* out0   = (float*)alloc((size_t)4096 * 512 * 4);
    float* out1   = (float*)alloc((size_t)4096 * 512 * 4);
    float* em     = (float*)alloc((size_t)4096 * 48 * 4);
    uint2* Wp0    = (uint2*)alloc((size_t)2 * 128 * 256 * 8);
    uint2* Wp1    = (uint2*)alloc((size_t)2 * 128 * 256 * 8);
    float* crfBT  = (float*)alloc((size_t)48 * 512 * 4);
    float* convWT = (float*)alloc((size_t)30000 * 4);

    const int prepN = 2 * 2 * 128 * 256 + 48 * 512 + 30000;
    prep<<<(prepN + 255) / 256, 256, 0, stream>>>(whh0, whh1, crfW, convW,
                                                  Wp0, Wp1, crfBT, convWT, outp);
    embed_conv<<<4096, 256, 0, stream>>>(iv, ov, ch, emb, ooevT, ctab, convWT, convB, inp);
    gemm_mfma<<<dim3(16, 32), 256, 0, stream>>>(inp, wih0, b0, xs, 4096, 2048, 500);
    lstm_rec<<<64, 256, 0, stream>>>(xs, Wp0, mask, out0);
    gemm_mfma<<<dim3(16, 32), 256, 0, stream>>>(out0, wih1, b1, xs, 4096, 2048, 512);
    lstm_rec<<<64, 256, 0, stream>>>(xs, Wp1, mask, out1);
    gemm_bt<<<dim3(1, 32), 256, 0, stream>>>(out1, crfBT, crfB, em, 4096, 48, 512);
    crf_loss<<<8, 192, 0, stream>>>(em, crfT, tgt, mask, outp);
}

// Round 8
// 7197.123 us; speedup vs baseline: 3.9440x; 3.9440x over previous
//
#include <hip/hip_runtime.h>
#include <hip/hip_bf16.h>

// Problem constants
// B=32, L=128, C=20, TOKEN_EMBED=300, CHAR_EMBED=50, NUM_FILTERS=200, KERNEL=3
// HID=256, LABELS=8, NS=6, D0=500, D1=512, BL=4096

typedef float floatx2 __attribute__((ext_vector_type(2)));
typedef short bf16x8 __attribute__((ext_vector_type(8)));
typedef float f32x4  __attribute__((ext_vector_type(4)));

__device__ __forceinline__ unsigned short f2bf(float x) {
    unsigned u = __float_as_uint(x);
    unsigned r = (u + 0x7fffu + ((u >> 16) & 1u)) >> 16;
    return (unsigned short)r;
}

// ---------------------------------------------------------------------------
// Prep: pack w_hh (both layers) to fp8 e4m3 as uint2 per (dir,k2,t):
//   .x = packed (i,f,g,o) for k=2*k2, .y = for k=2*k2+1.
// Also transpose crf_w / conv_w; zero d_out.
// ---------------------------------------------------------------------------
__global__ void prep(const float* __restrict__ wh0, const float* __restrict__ wh1,
                     const float* __restrict__ crf_w, const float* __restrict__ conv_w,
                     uint2* __restrict__ Wp0, uint2* __restrict__ Wp1,
                     float* __restrict__ crfBT, float* __restrict__ convWT,
                     float* __restrict__ outp)
{
    int idx = blockIdx.x * 256 + threadIdx.x;
    if (idx == 0) outp[0] = 0.f;
    const int NWP = 2 * 2 * 128 * 256;   // layer, dir, k2, t = 131072
    if (idx < NWP) {
        int layer = idx >> 16;
        int r     = idx & 65535;
        int dir   = r >> 15;
        int q     = r & 32767;
        int k2    = q >> 8;              // 0..127
        int t     = q & 255;
        const float* w = (layer ? wh1 : wh0) + dir * 1024 * 256;
        uint2 v;
        {
            int k = 2 * k2;
            float wi = w[(t      ) * 256 + k];
            float wf = w[(256 + t) * 256 + k];
            float wg = w[(512 + t) * 256 + k];
            float wo = w[(768 + t) * 256 + k];
            int u = __builtin_amdgcn_cvt_pk_fp8_f32(wi, wf, 0, false);
            u     = __builtin_amdgcn_cvt_pk_fp8_f32(wg, wo, u, true);
            v.x = (unsigned)u;
        }
        {
            int k = 2 * k2 + 1;
            float wi = w[(t      ) * 256 + k];
            float wf = w[(256 + t) * 256 + k];
            float wg = w[(512 + t) * 256 + k];
            float wo = w[(768 + t) * 256 + k];
            int u = __builtin_amdgcn_cvt_pk_fp8_f32(wi, wf, 0, false);
            u     = __builtin_amdgcn_cvt_pk_fp8_f32(wg, wo, u, true);
            v.y = (unsigned)u;
        }
        ((layer ? Wp1 : Wp0))[(size_t)dir * 32768 + k2 * 256 + t] = v;
        return;
    }
    idx -= NWP;
    if (idx < 48 * 512) {
        int jj = idx >> 9, d = idx & 511;
        int kL = jj / 6, n = jj % 6;
        crfBT[idx] = crf_w[(kL * 512 + d) * 6 + n];
        return;
    }
    idx -= 48 * 512;
    if (idx < 30000) {
        int f = idx % 200, ek = idx / 200;
        int e = ek / 3, kk = ek % 3;
        convWT[idx] = conv_w[(f * 50 + e) * 3 + kk];
        return;
    }
}

// ---------------------------------------------------------------------------
// Embeddings + char conv + concat -> inp (4096 x 500)
// ---------------------------------------------------------------------------
__global__ __launch_bounds__(256) void embed_conv(
    const int* __restrict__ iv, const int* __restrict__ ov, const int* __restrict__ ch,
    const float* __restrict__ emb, const float* __restrict__ ooev, const float* __restrict__ ctab,
    const float* __restrict__ convWT, const float* __restrict__ convB,
    float* __restrict__ inp)
{
    const int bl = blockIdx.x;
    const int tid = threadIdx.x;
    __shared__ float sx[50 * 20];
    const int ivv = iv[bl];
    const int ovv = ov[bl];
    const float mo = (ovv != 0) ? 1.f : 0.f;
    for (int e = tid; e < 300; e += 256)
        inp[bl * 500 + e] = emb[(size_t)ivv * 300 + e] + mo * ooev[(size_t)ovv * 300 + e];
    for (int i = tid; i < 1000; i += 256) {
        int cI = i / 50, e = i % 50;
        int id = ch[bl * 20 + cI];
        sx[e * 20 + cI] = id ? ctab[id * 50 + e] : 0.f;
    }
    __syncthreads();
    if (tid < 200) {
        float acc[22];
        float bz = convB[tid];
        #pragma unroll
        for (int o = 0; o < 22; ++o) acc[o] = bz;
        for (int e = 0; e < 50; ++e) {
            float xr[20];
            #pragma unroll
            for (int q = 0; q < 5; ++q) {
                float4 v = *(const float4*)&sx[e * 20 + q * 4];
                xr[q * 4 + 0] = v.x; xr[q * 4 + 1] = v.y;
                xr[q * 4 + 2] = v.z; xr[q * 4 + 3] = v.w;
            }
            float w0 = convWT[(e * 3 + 0) * 200 + tid];
            float w1 = convWT[(e * 3 + 1) * 200 + tid];
            float w2 = convWT[(e * 3 + 2) * 200 + tid];
            #pragma unroll
            for (int o = 0; o < 22; ++o) {
                float s = acc[o];
                if (o >= 2)            s = fmaf(xr[o - 2], w0, s);
                if (o >= 1 && o <= 20) s = fmaf(xr[o - 1], w1, s);
                if (o <= 19)           s = fmaf(xr[o],     w2, s);
                acc[o] = s;
            }
        }
        float mx = acc[0];
        #pragma unroll
        for (int o = 1; o < 22; ++o) mx = fmaxf(mx, acc[o]);
        inp[bl * 500 + 300 + tid] = 1.f / (1.f + expf(-mx));
    }
}

// ---------------------------------------------------------------------------
// MFMA bf16 GEMM (verified correct in R7: absmax 0.0)
// ---------------------------------------------------------------------------
__global__ __launch_bounds__(256) void gemm_mfma(
    const float* __restrict__ A, const float* __restrict__ Bm,
    const float* __restrict__ bias, float* __restrict__ C,
    int M, int N, int K)
{
    __shared__ unsigned short As[4][128][8];
    __shared__ unsigned short Bs[4][128][8];
    const int tid  = threadIdx.x;
    const int wave = tid >> 6, lane = tid & 63;
    const int quad = lane >> 4, lr = lane & 15;
    const int m0 = blockIdx.y * 128, n0 = blockIdx.x * 128;

    f32x4 acc[2][8];
    #pragma unroll
    for (int mt = 0; mt < 2; ++mt)
        #pragma unroll
        for (int nt = 0; nt < 8; ++nt) acc[mt][nt] = (f32x4){0.f, 0.f, 0.f, 0.f};

    const int ktiles = (K + 31) >> 5;
    for (int kt = 0; kt < ktiles; ++kt) {
        #pragma unroll
        for (int i = 0; i < 4; ++i) {
            int vid = tid + i * 256;
            int row = vid >> 3, kq = vid & 7;
            int kb  = kt * 32 + kq * 4;
            unsigned short ta[4], tb[4];
            const float* pa = A  + (size_t)(m0 + row) * K + kb;
            const float* pb = Bm + (size_t)(n0 + row) * K + kb;
            #pragma unroll
            for (int j = 0; j < 4; ++j) {
                ta[j] = (kb + j < K) ? f2bf(pa[j]) : (unsigned short)0;
                tb[j] = (kb + j < K) ? f2bf(pb[j]) : (unsigned short)0;
            }
            int ko = kq >> 1, jo = (kq & 1) * 4;
            *(ushort4*)&As[ko][row][jo] = make_ushort4(ta[0], ta[1], ta[2], ta[3]);
            *(ushort4*)&Bs[ko][row][jo] = make_ushort4(tb[0], tb[1], tb[2], tb[3]);
        }
        __syncthreads();
        bf16x8 bfr[8];
        #pragma unroll
        for (int nt = 0; nt < 8; ++nt)
            bfr[nt] = *(const bf16x8*)&Bs[quad][nt * 16 + lr][0];
        #pragma unroll
        for (int mt = 0; mt < 2; ++mt) {
            bf16x8 afr = *(const bf16x8*)&As[quad][wave * 32 + mt * 16 + lr][0];
            #pragma unroll
            for (int nt = 0; nt < 8; ++nt)
                acc[mt][nt] = __builtin_amdgcn_mfma_f32_16x16x32_bf16(
                    afr, bfr[nt], acc[mt][nt], 0, 0, 0);
        }
        __syncthreads();
    }
    #pragma unroll
    for (int mt = 0; mt < 2; ++mt)
        #pragma unroll
        for (int r = 0; r < 4; ++r) {
            int m = m0 + wave * 32 + mt * 16 + quad * 4 + r;
            #pragma unroll
            for (int nt = 0; nt < 8; ++nt) {
                int n = n0 + nt * 16 + lr;
                C[(size_t)m * N + n] = acc[mt][nt][r] + bias[n];
            }
        }
}

// ---------------------------------------------------------------------------
// fp32 GEMM (kept for the small emission GEMM, N=48)
// ---------------------------------------------------------------------------
__global__ __launch_bounds__(256) void gemm_bt(
    const float* __restrict__ A, const float* __restrict__ Bm,
    const float* __restrict__ bias, float* __restrict__ C,
    int M, int N, int K)
{
    __shared__ float At[16 * 128];
    __shared__ float Bt[16 * 128];
    const int tid = threadIdx.x;
    const int tx = tid & 15, ty = tid >> 4;
    const int m0 = blockIdx.y * 128, n0 = blockIdx.x * 128;
    float acc[2][2][4][4];
    #pragma unroll
    for (int a = 0; a < 2; ++a)
        #pragma unroll
        for (int b = 0; b < 2; ++b)
            #pragma unroll
            for (int i = 0; i < 4; ++i)
                #pragma unroll
                for (int j = 0; j < 4; ++j) acc[a][b][i][j] = 0.f;

    const int lr = tid >> 2;
    const int lc = (tid & 3) << 2;
    const int ktiles = (K + 15) >> 4;
    for (int kt = 0; kt < ktiles; ++kt) {
        const int k0 = kt << 4;
        #pragma unroll
        for (int half = 0; half < 2; ++half) {
            int r = lr + half * 64;
            int gk = k0 + lc;
            {
                int gm = m0 + r;
                float4 v = make_float4(0.f, 0.f, 0.f, 0.f);
                if (gm < M) {
                    const float* p = A + (size_t)gm * K + gk;
                    if (gk + 3 < K) v = *(const float4*)p;
                    else {
                        if (gk + 0 < K) v.x = p[0];
                        if (gk + 1 < K) v.y = p[1];
                        if (gk + 2 < K) v.z = p[2];
                        if (gk + 3 < K) v.w = p[3];
                    }
                }
                At[(lc + 0) * 128 + r] = v.x; At[(lc + 1) * 128 + r] = v.y;
                At[(lc + 2) * 128 + r] = v.z; At[(lc + 3) * 128 + r] = v.w;
            }
            {
                int gn = n0 + r;
                float4 v = make_float4(0.f, 0.f, 0.f, 0.f);
                if (gn < N) {
                    const float* p = Bm + (size_t)gn * K + gk;
                    if (gk + 3 < K) v = *(const float4*)p;
                    else {
                        if (gk + 0 < K) v.x = p[0];
                        if (gk + 1 < K) v.y = p[1];
                        if (gk + 2 < K) v.z = p[2];
                        if (gk + 3 < K) v.w = p[3];
                    }
                }
                Bt[(lc + 0) * 128 + r] = v.x; Bt[(lc + 1) * 128 + r] = v.y;
                Bt[(lc + 2) * 128 + r] = v.z; Bt[(lc + 3) * 128 + r] = v.w;
            }
        }
        __syncthreads();
        #pragma unroll
        for (int k = 0; k < 16; ++k) {
            float4 a0 = *(const float4*)&At[k * 128 + (ty << 2)];
            float4 a1 = *(const float4*)&At[k * 128 + 64 + (ty << 2)];
            float4 b0 = *(const float4*)&Bt[k * 128 + (tx << 2)];
            float4 b1 = *(const float4*)&Bt[k * 128 + 64 + (tx << 2)];
            float am[2][4] = {{a0.x, a0.y, a0.z, a0.w}, {a1.x, a1.y, a1.z, a1.w}};
            float bn[2][4] = {{b0.x, b0.y, b0.z, b0.w}, {b1.x, b1.y, b1.z, b1.w}};
            #pragma unroll
            for (int qa = 0; qa < 2; ++qa)
                #pragma unroll
                for (int qb = 0; qb < 2; ++qb)
                    #pragma unroll
                    for (int i = 0; i < 4; ++i)
                        #pragma unroll
                        for (int j = 0; j < 4; ++j)
                            acc[qa][qb][i][j] = fmaf(am[qa][i], bn[qb][j], acc[qa][qb][i][j]);
        }
        __syncthreads();
    }
    #pragma unroll
    for (int qa = 0; qa < 2; ++qa)
        #pragma unroll
        for (int i = 0; i < 4; ++i) {
            int m = m0 + qa * 64 + (ty << 2) + i;
            if (m >= M) continue;
            #pragma unroll
            for (int qb = 0; qb < 2; ++qb)
                #pragma unroll
                for (int j = 0; j < 4; ++j) {
                    int n = n0 + qb * 64 + (tx << 2) + j;
                    if (n < N) C[(size_t)m * N + n] = acc[qa][qb][i][j] + bias[n];
                }
        }
}

// ---------------------------------------------------------------------------
// LSTM recurrence v8: HYBRID stationary weights, zero per-step streaming.
//  - k2 in [0,64):   wreg[64] uint2 = 128 VGPRs (arch cap is 256 - R7 lesson)
//  - k2 in [64,128): LDS wlds = 64*256 uint2 = 128 KB (gfx950 LDS = 160 KB)
// 64 blocks = (b, dir), 256 threads = t (thread t computes all gates of t).
// Per step: issue-bound ~1650 instr (cvt+fma+ds_read) ~= 1.3 us/step.
// ---------------------------------------------------------------------------
__global__ __launch_bounds__(256, 1) void lstm_rec(
    const float* __restrict__ xs, const uint2* __restrict__ Wp,
    const float* __restrict__ mask, float* __restrict__ out)
{
    const int t   = threadIdx.x;
    const int b   = blockIdx.x >> 1;
    const int dir = blockIdx.x & 1;
    __shared__ uint2 wlds[64 * 256];     // 128 KB: k2 in [64,128)
    __shared__ float hs[256];
    __shared__ float msk[128];

    const uint2* wp = Wp + (size_t)dir * 32768;
    // one-time fills
    uint2 wreg[64];
    #pragma unroll
    for (int j = 0; j < 64; ++j) wreg[j] = wp[j * 256 + t];
    for (int j = 0; j < 64; ++j) wlds[j * 256 + t] = wp[(64 + j) * 256 + t];
    hs[t] = 0.f;
    if (t < 128) msk[t] = mask[b * 128 + t];
    __syncthreads();

    float h = 0.f, c = 0.f;
    for (int s = 0; s < 128; ++s) {
        const int l = dir ? (127 - s) : s;
        const float* gx = xs + ((size_t)(b * 128 + l) * 2048 + dir * 1024 + t);
        float gi = gx[0], gf = gx[256], gg2 = gx[512], go = gx[768];
        floatx2 aif = {0.f, 0.f}, ago = {0.f, 0.f};
        #pragma unroll
        for (int k2 = 0; k2 < 64; ++k2) {
            uint2 w = wreg[k2];
            float2 hv = *(const float2*)&hs[k2 * 2];     // wave-uniform bcast
            floatx2 lo0 = __builtin_amdgcn_cvt_pk_f32_fp8((int)w.x, false);
            floatx2 hi0 = __builtin_amdgcn_cvt_pk_f32_fp8((int)w.x, true);
            floatx2 lo1 = __builtin_amdgcn_cvt_pk_f32_fp8((int)w.y, false);
            floatx2 hi1 = __builtin_amdgcn_cvt_pk_f32_fp8((int)w.y, true);
            floatx2 hx = {hv.x, hv.x}, hy = {hv.y, hv.y};
            aif += hx * lo0; ago += hx * hi0;
            aif += hy * lo1; ago += hy * hi1;
        }
        #pragma unroll
        for (int k2 = 0; k2 < 64; ++k2) {
            uint2 w = wlds[k2 * 256 + t];
            float2 hv = *(const float2*)&hs[128 + k2 * 2];
            floatx2 lo0 = __builtin_amdgcn_cvt_pk_f32_fp8((int)w.x, false);
            floatx2 hi0 = __builtin_amdgcn_cvt_pk_f32_fp8((int)w.x, true);
            floatx2 lo1 = __builtin_amdgcn_cvt_pk_f32_fp8((int)w.y, false);
            floatx2 hi1 = __builtin_amdgcn_cvt_pk_f32_fp8((int)w.y, true);
            floatx2 hx = {hv.x, hv.x}, hy = {hv.y, hv.y};
            aif += hx * lo0; ago += hx * hi0;
            aif += hy * lo1; ago += hy * hi1;
        }
        const float m = msk[l];
        float ig = 1.f / (1.f + __expf(-(aif.x + gi)));
        float fg = 1.f / (1.f + __expf(-(aif.y + gf)));
        float gg = tanhf(ago.x + gg2);
        float og = 1.f / (1.f + __expf(-(ago.y + go)));
        float cn = fmaf(fg, c, ig * gg);
        float hn = og * tanhf(cn);
        h = m * hn + (1.f - m) * h;
        c = m * cn + (1.f - m) * c;
        __syncthreads();            // all lanes done reading hs of prev step
        hs[t] = h;
        out[(size_t)(b * 128 + l) * 512 + dir * 256 + t] = h;
        __syncthreads();            // new hs visible before next step's reads
    }
}

// ---------------------------------------------------------------------------
// CRF loss: 8 blocks (one per label k), 192 threads = (b in 0..31, j in 0..5)
// ---------------------------------------------------------------------------
__global__ __launch_bounds__(192) void crf_loss(
    const float* __restrict__ em, const float* __restrict__ trans,
    const int* __restrict__ target, const float* __restrict__ mask,
    float* __restrict__ outp)
{
    const int k = blockIdx.x;
    const int tid = threadIdx.x;
    const int b = tid & 31;
    const int j = tid >> 5;
    __shared__ float T[36];
    __shared__ float As[32][6];
    __shared__ float red[192];
    if (tid < 36) T[tid] = trans[k * 36 + tid];
    __syncthreads();
    const int* tg = target + (k * 32 + b) * 128;
    float sc = 0.f;
    for (int l = j; l < 128; l += 6) {
        int y = tg[l];
        float m = mask[b * 128 + l];
        sc += m * em[(b * 128 + l) * 48 + k * 6 + y];
        if (l > 0) sc += m * T[tg[l - 1] * 6 + y];
    }
    red[tid] = sc;
    float a = em[(b * 128) * 48 + k * 6 + j];
    As[b][j] = a;
    __syncthreads();
    for (int l = 1; l < 128; ++l) {
        float e = em[(b * 128 + l) * 48 + k * 6 + j];
        float v0 = As[b][0] + T[0 * 6 + j];
        float v1 = As[b][1] + T[1 * 6 + j];
        float v2 = As[b][2] + T[2 * 6 + j];
        float v3 = As[b][3] + T[3 * 6 + j];
        float v4 = As[b][4] + T[4 * 6 + j];
        float v5 = As[b][5] + T[5 * 6 + j];
        float mx = fmaxf(fmaxf(fmaxf(v0, v1), fmaxf(v2, v3)), fmaxf(v4, v5));
        float ssum = expf(v0 - mx) + expf(v1 - mx) + expf(v2 - mx)
                   + expf(v3 - mx) + expf(v4 - mx) + expf(v5 - mx);
        float na = mx + logf(ssum) + e;
        float m = mask[b * 128 + l];
        a = m * na + (1.f - m) * a;
        __syncthreads();
        As[b][j] = a;
        __syncthreads();
    }
    if (j == 0) {
        float v0 = As[b][0], v1 = As[b][1], v2 = As[b][2];
        float v3 = As[b][3], v4 = As[b][4], v5 = As[b][5];
        float mx = fmaxf(fmaxf(fmaxf(v0, v1), fmaxf(v2, v3)), fmaxf(v4, v5));
        float ssum = expf(v0 - mx) + expf(v1 - mx) + expf(v2 - mx)
                   + expf(v3 - mx) + expf(v4 - mx) + expf(v5 - mx);
        float logZ = mx + logf(ssum);
        float scb = red[b] + red[b + 32] + red[b + 64] + red[b + 96] + red[b + 128] + red[b + 160];
        red[b] = logZ - scb;
    }
    __syncthreads();
    if (tid == 0) {
        float tot = 0.f;
        for (int bb = 0; bb < 32; ++bb) tot += red[bb];
        atomicAdd(outp, tot * (1.f / 32.f));
    }
}

// ---------------------------------------------------------------------------
extern "C" void kernel_launch(void* const* d_in, const int* in_sizes, int n_in,
                              void* d_out, int out_size, void* d_ws, size_t ws_size,
                              hipStream_t stream)
{
    const int*   iv    = (const int*)d_in[0];
    const int*   ov    = (const int*)d_in[1];
    const int*   ch    = (const int*)d_in[2];
    const int*   tgt   = (const int*)d_in[3];
    const float* mask  = (const float*)d_in[4];
    const float* emb   = (const float*)d_in[5];
    const float* ooevT = (const float*)d_in[6];
    const float* ctab  = (const float*)d_in[7];
    const float* convW = (const float*)d_in[8];
    const float* convB = (const float*)d_in[9];
    const float* wih0  = (const float*)d_in[10];
    const float* whh0  = (const float*)d_in[11];
    const float* b0    = (const float*)d_in[12];
    const float* wih1  = (const float*)d_in[13];
    const float* whh1  = (const float*)d_in[14];
    const float* b1    = (const float*)d_in[15];
    const float* crfW  = (const float*)d_in[16];
    const float* crfB  = (const float*)d_in[17];
    const float* crfT  = (const float*)d_in[18];
    float* outp = (float*)d_out;

    char* ws = (char*)d_ws;
    size_t off = 0;
    auto alloc = [&](size_t bytes) {
        void* p = ws + off;
        off = (off + bytes + 255) & ~(size_t)255;
        return p;
    };
    float* inp    = (float*)alloc((size_t)4096 * 500 * 4);
    float* xs     = (float*)alloc((size_t)4096 * 2048 * 4);
    float* out0   = (float*)alloc((size_t)4096 * 512 * 4);
    float* out1   = (float*)alloc((size_t)4096 * 512 * 4);
    float* em     = (float*)alloc((size_t)4096 * 48 * 4);
    uint2* Wp0    = (uint2*)alloc((size_t)2 * 128 * 256 * 8);
    uint2* Wp1    = (uint2*)alloc((size_t)2 * 128 * 256 * 8);
    float* crfBT  = (float*)alloc((size_t)48 * 512 * 4);
    float* convWT = (float*)alloc((size_t)30000 * 4);

    const int prepN = 2 * 2 * 128 * 256 + 48 * 512 + 30000;
    prep<<<(prepN + 255) / 256, 256, 0, stream>>>(whh0, whh1, crfW, convW,
                                                  Wp0, Wp1, crfBT, convWT, outp);
    embed_conv<<<4096, 256, 0, stream>>>(iv, ov, ch, emb, ooevT, ctab, convWT, convB, inp);
    gemm_mfma<<<dim3(16, 32), 256, 0, stream>>>(inp, wih0, b0, xs, 4096, 2048, 500);
    lstm_rec<<<64, 256, 0, stream>>>(xs, Wp0, mask, out0);
    gemm_mfma<<<dim3(16, 32), 256, 0, stream>>>(out0, wih1, b1, xs, 4096, 2048, 512);
    lstm_rec<<<64, 256, 0, stream>>>(xs, Wp1, mask, out1);
    gemm_bt<<<dim3(1, 32), 256, 0, stream>>>(out1, crfBT, crfB, em, 4096, 48, 512);
    crf_loss<<<8, 192, 0, stream>>>(em, crfT, tgt, mask, outp);
}

// Round 9
// 1968.666 us; speedup vs baseline: 14.4185x; 3.6558x over previous
//
#include <hip/hip_runtime.h>
#include <hip/hip_bf16.h>

// Problem constants
// B=32, L=128, C=20, TOKEN_EMBED=300, CHAR_EMBED=50, NUM_FILTERS=200, KERNEL=3
// HID=256, LABELS=8, NS=6, D0=500, D1=512, BL=4096

typedef float floatx2 __attribute__((ext_vector_type(2)));
typedef short bf16x8 __attribute__((ext_vector_type(8)));
typedef float f32x4  __attribute__((ext_vector_type(4)));

__device__ __forceinline__ unsigned short f2bf(float x) {
    unsigned u = __float_as_uint(x);
    unsigned r = (u + 0x7fffu + ((u >> 16) & 1u)) >> 16;
    return (unsigned short)r;
}

// ---------------------------------------------------------------------------
// Prep: pack w_hh (both layers) to fp8 e4m3 as uint2 per (dir,k2,t):
//   .x = packed (i,f,g,o) for k=2*k2, .y = for k=2*k2+1.
// Also transpose crf_w / conv_w; zero d_out.
// ---------------------------------------------------------------------------
__global__ void prep(const float* __restrict__ wh0, const float* __restrict__ wh1,
                     const float* __restrict__ crf_w, const float* __restrict__ conv_w,
                     uint2* __restrict__ Wp0, uint2* __restrict__ Wp1,
                     float* __restrict__ crfBT, float* __restrict__ convWT,
                     float* __restrict__ outp)
{
    int idx = blockIdx.x * 256 + threadIdx.x;
    if (idx == 0) outp[0] = 0.f;
    const int NWP = 2 * 2 * 128 * 256;   // layer, dir, k2, t = 131072
    if (idx < NWP) {
        int layer = idx >> 16;
        int r     = idx & 65535;
        int dir   = r >> 15;
        int q     = r & 32767;
        int k2    = q >> 8;              // 0..127
        int t     = q & 255;
        const float* w = (layer ? wh1 : wh0) + dir * 1024 * 256;
        uint2 v;
        {
            int k = 2 * k2;
            float wi = w[(t      ) * 256 + k];
            float wf = w[(256 + t) * 256 + k];
            float wg = w[(512 + t) * 256 + k];
            float wo = w[(768 + t) * 256 + k];
            int u = __builtin_amdgcn_cvt_pk_fp8_f32(wi, wf, 0, false);
            u     = __builtin_amdgcn_cvt_pk_fp8_f32(wg, wo, u, true);
            v.x = (unsigned)u;
        }
        {
            int k = 2 * k2 + 1;
            float wi = w[(t      ) * 256 + k];
            float wf = w[(256 + t) * 256 + k];
            float wg = w[(512 + t) * 256 + k];
            float wo = w[(768 + t) * 256 + k];
            int u = __builtin_amdgcn_cvt_pk_fp8_f32(wi, wf, 0, false);
            u     = __builtin_amdgcn_cvt_pk_fp8_f32(wg, wo, u, true);
            v.y = (unsigned)u;
        }
        ((layer ? Wp1 : Wp0))[(size_t)dir * 32768 + k2 * 256 + t] = v;
        return;
    }
    idx -= NWP;
    if (idx < 48 * 512) {
        int jj = idx >> 9, d = idx & 511;
        int kL = jj / 6, n = jj % 6;
        crfBT[idx] = crf_w[(kL * 512 + d) * 6 + n];
        return;
    }
    idx -= 48 * 512;
    if (idx < 30000) {
        int f = idx % 200, ek = idx / 200;
        int e = ek / 3, kk = ek % 3;
        convWT[idx] = conv_w[(f * 50 + e) * 3 + kk];
        return;
    }
}

// ---------------------------------------------------------------------------
// Embeddings + char conv + concat -> inp (4096 x 500)
// ---------------------------------------------------------------------------
__global__ __launch_bounds__(256) void embed_conv(
    const int* __restrict__ iv, const int* __restrict__ ov, const int* __restrict__ ch,
    const float* __restrict__ emb, const float* __restrict__ ooev, const float* __restrict__ ctab,
    const float* __restrict__ convWT, const float* __restrict__ convB,
    float* __restrict__ inp)
{
    const int bl = blockIdx.x;
    const int tid = threadIdx.x;
    __shared__ float sx[50 * 20];
    const int ivv = iv[bl];
    const int ovv = ov[bl];
    const float mo = (ovv != 0) ? 1.f : 0.f;
    for (int e = tid; e < 300; e += 256)
        inp[bl * 500 + e] = emb[(size_t)ivv * 300 + e] + mo * ooev[(size_t)ovv * 300 + e];
    for (int i = tid; i < 1000; i += 256) {
        int cI = i / 50, e = i % 50;
        int id = ch[bl * 20 + cI];
        sx[e * 20 + cI] = id ? ctab[id * 50 + e] : 0.f;
    }
    __syncthreads();
    if (tid < 200) {
        float acc[22];
        float bz = convB[tid];
        #pragma unroll
        for (int o = 0; o < 22; ++o) acc[o] = bz;
        for (int e = 0; e < 50; ++e) {
            float xr[20];
            #pragma unroll
            for (int q = 0; q < 5; ++q) {
                float4 v = *(const float4*)&sx[e * 20 + q * 4];
                xr[q * 4 + 0] = v.x; xr[q * 4 + 1] = v.y;
                xr[q * 4 + 2] = v.z; xr[q * 4 + 3] = v.w;
            }
            float w0 = convWT[(e * 3 + 0) * 200 + tid];
            float w1 = convWT[(e * 3 + 1) * 200 + tid];
            float w2 = convWT[(e * 3 + 2) * 200 + tid];
            #pragma unroll
            for (int o = 0; o < 22; ++o) {
                float s = acc[o];
                if (o >= 2)            s = fmaf(xr[o - 2], w0, s);
                if (o >= 1 && o <= 20) s = fmaf(xr[o - 1], w1, s);
                if (o <= 19)           s = fmaf(xr[o],     w2, s);
                acc[o] = s;
            }
        }
        float mx = acc[0];
        #pragma unroll
        for (int o = 1; o < 22; ++o) mx = fmaxf(mx, acc[o]);
        inp[bl * 500 + 300 + tid] = 1.f / (1.f + expf(-mx));
    }
}

// ---------------------------------------------------------------------------
// MFMA bf16 GEMM (verified correct in R7/R8: absmax 0.0)
// ---------------------------------------------------------------------------
__global__ __launch_bounds__(256) void gemm_mfma(
    const float* __restrict__ A, const float* __restrict__ Bm,
    const float* __restrict__ bias, float* __restrict__ C,
    int M, int N, int K)
{
    __shared__ unsigned short As[4][128][8];
    __shared__ unsigned short Bs[4][128][8];
    const int tid  = threadIdx.x;
    const int wave = tid >> 6, lane = tid & 63;
    const int quad = lane >> 4, lr = lane & 15;
    const int m0 = blockIdx.y * 128, n0 = blockIdx.x * 128;

    f32x4 acc[2][8];
    #pragma unroll
    for (int mt = 0; mt < 2; ++mt)
        #pragma unroll
        for (int nt = 0; nt < 8; ++nt) acc[mt][nt] = (f32x4){0.f, 0.f, 0.f, 0.f};

    const int ktiles = (K + 31) >> 5;
    for (int kt = 0; kt < ktiles; ++kt) {
        #pragma unroll
        for (int i = 0; i < 4; ++i) {
            int vid = tid + i * 256;
            int row = vid >> 3, kq = vid & 7;
            int kb  = kt * 32 + kq * 4;
            unsigned short ta[4], tb[4];
            const float* pa = A  + (size_t)(m0 + row) * K + kb;
            const float* pb = Bm + (size_t)(n0 + row) * K + kb;
            #pragma unroll
            for (int j = 0; j < 4; ++j) {
                ta[j] = (kb + j < K) ? f2bf(pa[j]) : (unsigned short)0;
                tb[j] = (kb + j < K) ? f2bf(pb[j]) : (unsigned short)0;
            }
            int ko = kq >> 1, jo = (kq & 1) * 4;
            *(ushort4*)&As[ko][row][jo] = make_ushort4(ta[0], ta[1], ta[2], ta[3]);
            *(ushort4*)&Bs[ko][row][jo] = make_ushort4(tb[0], tb[1], tb[2], tb[3]);
        }
        __syncthreads();
        bf16x8 bfr[8];
        #pragma unroll
        for (int nt = 0; nt < 8; ++nt)
            bfr[nt] = *(const bf16x8*)&Bs[quad][nt * 16 + lr][0];
        #pragma unroll
        for (int mt = 0; mt < 2; ++mt) {
            bf16x8 afr = *(const bf16x8*)&As[quad][wave * 32 + mt * 16 + lr][0];
            #pragma unroll
            for (int nt = 0; nt < 8; ++nt)
                acc[mt][nt] = __builtin_amdgcn_mfma_f32_16x16x32_bf16(
                    afr, bfr[nt], acc[mt][nt], 0, 0, 0);
        }
        __syncthreads();
    }
    #pragma unroll
    for (int mt = 0; mt < 2; ++mt)
        #pragma unroll
        for (int r = 0; r < 4; ++r) {
            int m = m0 + wave * 32 + mt * 16 + quad * 4 + r;
            #pragma unroll
            for (int nt = 0; nt < 8; ++nt) {
                int n = n0 + nt * 16 + lr;
                C[(size_t)m * N + n] = acc[mt][nt][r] + bias[n];
            }
        }
}

// ---------------------------------------------------------------------------
// fp32 GEMM (kept for the small emission GEMM, N=48)
// ---------------------------------------------------------------------------
__global__ __launch_bounds__(256) void gemm_bt(
    const float* __restrict__ A, const float* __restrict__ Bm,
    const float* __restrict__ bias, float* __restrict__ C,
    int M, int N, int K)
{
    __shared__ float At[16 * 128];
    __shared__ float Bt[16 * 128];
    const int tid = threadIdx.x;
    const int tx = tid & 15, ty = tid >> 4;
    const int m0 = blockIdx.y * 128, n0 = blockIdx.x * 128;
    float acc[2][2][4][4];
    #pragma unroll
    for (int a = 0; a < 2; ++a)
        #pragma unroll
        for (int b = 0; b < 2; ++b)
            #pragma unroll
            for (int i = 0; i < 4; ++i)
                #pragma unroll
                for (int j = 0; j < 4; ++j) acc[a][b][i][j] = 0.f;

    const int lr = tid >> 2;
    const int lc = (tid & 3) << 2;
    const int ktiles = (K + 15) >> 4;
    for (int kt = 0; kt < ktiles; ++kt) {
        const int k0 = kt << 4;
        #pragma unroll
        for (int half = 0; half < 2; ++half) {
            int r = lr + half * 64;
            int gk = k0 + lc;
            {
                int gm = m0 + r;
                float4 v = make_float4(0.f, 0.f, 0.f, 0.f);
                if (gm < M) {
                    const float* p = A + (size_t)gm * K + gk;
                    if (gk + 3 < K) v = *(const float4*)p;
                    else {
                        if (gk + 0 < K) v.x = p[0];
                        if (gk + 1 < K) v.y = p[1];
                        if (gk + 2 < K) v.z = p[2];
                        if (gk + 3 < K) v.w = p[3];
                    }
                }
                At[(lc + 0) * 128 + r] = v.x; At[(lc + 1) * 128 + r] = v.y;
                At[(lc + 2) * 128 + r] = v.z; At[(lc + 3) * 128 + r] = v.w;
            }
            {
                int gn = n0 + r;
                float4 v = make_float4(0.f, 0.f, 0.f, 0.f);
                if (gn < N) {
                    const float* p = Bm + (size_t)gn * K + gk;
                    if (gk + 3 < K) v = *(const float4*)p;
                    else {
                        if (gk + 0 < K) v.x = p[0];
                        if (gk + 1 < K) v.y = p[1];
                        if (gk + 2 < K) v.z = p[2];
                        if (gk + 3 < K) v.w = p[3];
                    }
                }
                Bt[(lc + 0) * 128 + r] = v.x; Bt[(lc + 1) * 128 + r] = v.y;
                Bt[(lc + 2) * 128 + r] = v.z; Bt[(lc + 3) * 128 + r] = v.w;
            }
        }
        __syncthreads();
        #pragma unroll
        for (int k = 0; k < 16; ++k) {
            float4 a0 = *(const float4*)&At[k * 128 + (ty << 2)];
            float4 a1 = *(const float4*)&At[k * 128 + 64 + (ty << 2)];
            float4 b0 = *(const float4*)&Bt[k * 128 + (tx << 2)];
            float4 b1 = *(const float4*)&Bt[k * 128 + 64 + (tx << 2)];
            float am[2][4] = {{a0.x, a0.y, a0.z, a0.w}, {a1.x, a1.y, a1.z, a1.w}};
            float bn[2][4] = {{b0.x, b0.y, b0.z, b0.w}, {b1.x, b1.y, b1.z, b1.w}};
            #pragma unroll
            for (int qa = 0; qa < 2; ++qa)
                #pragma unroll
                for (int qb = 0; qb < 2; ++qb)
                    #pragma unroll
                    for (int i = 0; i < 4; ++i)
                        #pragma unroll
                        for (int j = 0; j < 4; ++j)
                            acc[qa][qb][i][j] = fmaf(am[qa][i], bn[qb][j], acc[qa][qb][i][j]);
        }
        __syncthreads();
    }
    #pragma unroll
    for (int qa = 0; qa < 2; ++qa)
        #pragma unroll
        for (int i = 0; i < 4; ++i) {
            int m = m0 + qa * 64 + (ty << 2) + i;
            if (m >= M) continue;
            #pragma unroll
            for (int qb = 0; qb < 2; ++qb)
                #pragma unroll
                for (int j = 0; j < 4; ++j) {
                    int n = n0 + qb * 64 + (tx << 2) + j;
                    if (n < N) C[(size_t)m * N + n] = acc[qa][qb][i][j] + bias[n];
                }
        }
}

// ---------------------------------------------------------------------------
// LSTM recurrence v9: LDS-stationary majority + streamed minority.
//  - k2 in [0,76):    LDS wlds = 76*256 uint2 = 152 KB (gfx950 LDS 160 KB;
//                     >64 KB proven working in R8)
//  - k2 in [76,128):  streamed from L2 (104 KB/step @ ~24 B/cy/CU ~ 1.8 us)
// NO register weight arrays (R4/R5/R7/R8 all spilled at the 256-VGPR arch
// cap). 64 blocks = (b,dir), 256 threads = t. VGPR ~50.
// ---------------------------------------------------------------------------
#define KL 76
__global__ __launch_bounds__(256, 1) void lstm_rec(
    const float* __restrict__ xs, const uint2* __restrict__ Wp,
    const float* __restrict__ mask, float* __restrict__ out)
{
    const int t   = threadIdx.x;
    const int b   = blockIdx.x >> 1;
    const int dir = blockIdx.x & 1;
    __shared__ uint2 wlds[KL * 256];     // 152 KB
    __shared__ float hs[256];
    __shared__ float msk[128];

    const uint2* wp = Wp + (size_t)dir * 32768;
    for (int j = 0; j < KL; ++j) wlds[j * 256 + t] = wp[j * 256 + t];
    hs[t] = 0.f;
    if (t < 128) msk[t] = mask[b * 128 + t];
    __syncthreads();

    const uint2* ws = wp + KL * 256 + t;   // streamed tail: k2 in [KL,128)
    float h = 0.f, c = 0.f;
    for (int s = 0; s < 128; ++s) {
        const int l = dir ? (127 - s) : s;
        const float* gx = xs + ((size_t)(b * 128 + l) * 2048 + dir * 1024 + t);
        float gi = gx[0], gf = gx[256], gg2 = gx[512], go = gx[768];
        floatx2 aif = {0.f, 0.f}, ago = {0.f, 0.f};
        // streamed half first: loads issued early, overlap LDS-half compute
        #pragma unroll 4
        for (int k2 = 0; k2 < 128 - KL; ++k2) {
            uint2 w = ws[k2 * 256];                        // coalesced 8B/lane
            float2 hv = *(const float2*)&hs[(KL + k2) * 2];
            floatx2 lo0 = __builtin_amdgcn_cvt_pk_f32_fp8((int)w.x, false);
            floatx2 hi0 = __builtin_amdgcn_cvt_pk_f32_fp8((int)w.x, true);
            floatx2 lo1 = __builtin_amdgcn_cvt_pk_f32_fp8((int)w.y, false);
            floatx2 hi1 = __builtin_amdgcn_cvt_pk_f32_fp8((int)w.y, true);
            floatx2 hx = {hv.x, hv.x}, hy = {hv.y, hv.y};
            aif += hx * lo0; ago += hx * hi0;
            aif += hy * lo1; ago += hy * hi1;
        }
        #pragma unroll 4
        for (int k2 = 0; k2 < KL; ++k2) {
            uint2 w = wlds[k2 * 256 + t];                  // 2-way = free
            float2 hv = *(const float2*)&hs[k2 * 2];       // wave-uniform bcast
            floatx2 lo0 = __builtin_amdgcn_cvt_pk_f32_fp8((int)w.x, false);
            floatx2 hi0 = __builtin_amdgcn_cvt_pk_f32_fp8((int)w.x, true);
            floatx2 lo1 = __builtin_amdgcn_cvt_pk_f32_fp8((int)w.y, false);
            floatx2 hi1 = __builtin_amdgcn_cvt_pk_f32_fp8((int)w.y, true);
            floatx2 hx = {hv.x, hv.x}, hy = {hv.y, hv.y};
            aif += hx * lo0; ago += hx * hi0;
            aif += hy * lo1; ago += hy * hi1;
        }
        const float m = msk[l];
        float ig = 1.f / (1.f + __expf(-(aif.x + gi)));
        float fg = 1.f / (1.f + __expf(-(aif.y + gf)));
        float gg = tanhf(ago.x + gg2);
        float og = 1.f / (1.f + __expf(-(ago.y + go)));
        float cn = fmaf(fg, c, ig * gg);
        float hn = og * tanhf(cn);
        h = m * hn + (1.f - m) * h;
        c = m * cn + (1.f - m) * c;
        __syncthreads();            // all lanes done reading hs of prev step
        hs[t] = h;
        out[(size_t)(b * 128 + l) * 512 + dir * 256 + t] = h;
        __syncthreads();            // new hs visible before next step's reads
    }
}
#undef KL

// ---------------------------------------------------------------------------
// CRF loss: 8 blocks (one per label k), 192 threads = (b in 0..31, j in 0..5)
// ---------------------------------------------------------------------------
__global__ __launch_bounds__(192) void crf_loss(
    const float* __restrict__ em, const float* __restrict__ trans,
    const int* __restrict__ target, const float* __restrict__ mask,
    float* __restrict__ outp)
{
    const int k = blockIdx.x;
    const int tid = threadIdx.x;
    const int b = tid & 31;
    const int j = tid >> 5;
    __shared__ float T[36];
    __shared__ float As[32][6];
    __shared__ float red[192];
    if (tid < 36) T[tid] = trans[k * 36 + tid];
    __syncthreads();
    const int* tg = target + (k * 32 + b) * 128;
    float sc = 0.f;
    for (int l = j; l < 128; l += 6) {
        int y = tg[l];
        float m = mask[b * 128 + l];
        sc += m * em[(b * 128 + l) * 48 + k * 6 + y];
        if (l > 0) sc += m * T[tg[l - 1] * 6 + y];
    }
    red[tid] = sc;
    float a = em[(b * 128) * 48 + k * 6 + j];
    As[b][j] = a;
    __syncthreads();
    for (int l = 1; l < 128; ++l) {
        float e = em[(b * 128 + l) * 48 + k * 6 + j];
        float v0 = As[b][0] + T[0 * 6 + j];
        float v1 = As[b][1] + T[1 * 6 + j];
        float v2 = As[b][2] + T[2 * 6 + j];
        float v3 = As[b][3] + T[3 * 6 + j];
        float v4 = As[b][4] + T[4 * 6 + j];
        float v5 = As[b][5] + T[5 * 6 + j];
        float mx = fmaxf(fmaxf(fmaxf(v0, v1), fmaxf(v2, v3)), fmaxf(v4, v5));
        float ssum = expf(v0 - mx) + expf(v1 - mx) + expf(v2 - mx)
                   + expf(v3 - mx) + expf(v4 - mx) + expf(v5 - mx);
        float na = mx + logf(ssum) + e;
        float m = mask[b * 128 + l];
        a = m * na + (1.f - m) * a;
        __syncthreads();
        As[b][j] = a;
        __syncthreads();
    }
    if (j == 0) {
        float v0 = As[b][0], v1 = As[b][1], v2 = As[b][2];
        float v3 = As[b][3], v4 = As[b][4], v5 = As[b][5];
        float mx = fmaxf(fmaxf(fmaxf(v0, v1), fmaxf(v2, v3)), fmaxf(v4, v5));
        float ssum = expf(v0 - mx) + expf(v1 - mx) + expf(v2 - mx)
                   + expf(v3 - mx) + expf(v4 - mx) + expf(v5 - mx);
        float logZ = mx + logf(ssum);
        float scb = red[b] + red[b + 32] + red[b + 64] + red[b + 96] + red[b + 128] + red[b + 160];
        red[b] = logZ - scb;
    }
    __syncthreads();
    if (tid == 0) {
        float tot = 0.f;
        for (int bb = 0; bb < 32; ++bb) tot += red[bb];
        atomicAdd(outp, tot * (1.f / 32.f));
    }
}

// ---------------------------------------------------------------------------
extern "C" void kernel_launch(void* const* d_in, const int* in_sizes, int n_in,
                              void* d_out, int out_size, void* d_ws, size_t ws_size,
                              hipStream_t stream)
{
    const int*   iv    = (const int*)d_in[0];
    const int*   ov    = (const int*)d_in[1];
    const int*   ch    = (const int*)d_in[2];
    const int*   tgt   = (const int*)d_in[3];
    const float* mask  = (const float*)d_in[4];
    const float* emb   = (const float*)d_in[5];
    const float* ooevT = (const float*)d_in[6];
    const float* ctab  = (const float*)d_in[7];
    const float* convW = (const float*)d_in[8];
    const float* convB = (const float*)d_in[9];
    const float* wih0  = (const float*)d_in[10];
    const float* whh0  = (const float*)d_in[11];
    const float* b0    = (const float*)d_in[12];
    const float* wih1  = (const float*)d_in[13];
    const float* whh1  = (const float*)d_in[14];
    const float* b1    = (const float*)d_in[15];
    const float* crfW  = (const float*)d_in[16];
    const float* crfB  = (const float*)d_in[17];
    const float* crfT  = (const float*)d_in[18];
    float* outp = (float*)d_out;

    char* ws = (char*)d_ws;
    size_t off = 0;
    auto alloc = [&](size_t bytes) {
        void* p = ws + off;
        off = (off + bytes + 255) & ~(size_t)255;
        return p;
    };
    float* inp    = (float*)alloc((size_t)4096 * 500 * 4);
    float* xs     = (float*)alloc((size_t)4096 * 2048 * 4);
    float* out0   = (float*)alloc((size_t)4096 * 512 * 4);
    float* out1   = (float*)alloc((size_t)4096 * 512 * 4);
    float* em     = (float*)alloc((size_t)4096 * 48 * 4);
    uint2* Wp0    = (uint2*)alloc((size_t)2 * 128 * 256 * 8);
    uint2* Wp1    = (uint2*)alloc((size_t)2 * 128 * 256 * 8);
    float* crfBT  = (float*)alloc((size_t)48 * 512 * 4);
    float* convWT = (float*)alloc((size_t)30000 * 4);

    const int prepN = 2 * 2 * 128 * 256 + 48 * 512 + 30000;
    prep<<<(prepN + 255) / 256, 256, 0, stream>>>(whh0, whh1, crfW, convW,
                                                  Wp0, Wp1, crfBT, convWT, outp);
    embed_conv<<<4096, 256, 0, stream>>>(iv, ov, ch, emb, ooevT, ctab, convWT, convB, inp);
    gemm_mfma<<<dim3(16, 32), 256, 0, stream>>>(inp, wih0, b0, xs, 4096, 2048, 500);
    lstm_rec<<<64, 256, 0, stream>>>(xs, Wp0, mask, out0);
    gemm_mfma<<<dim3(16, 32), 256, 0, stream>>>(out0, wih1, b1, xs, 4096, 2048, 512);
    lstm_rec<<<64, 256, 0, stream>>>(xs, Wp1, mask, out1);
    gemm_bt<<<dim3(1, 32), 256, 0, stream>>>(out1, crfBT, crfB, em, 4096, 48, 512);
    crf_loss<<<8, 192, 0, stream>>>(em, crfT, tgt, mask, outp);
}

// Round 10
// 1506.083 us; speedup vs baseline: 18.8470x; 1.3071x over previous
//
#include <hip/hip_runtime.h>
#include <hip/hip_bf16.h>

// Problem constants
// B=32, L=128, C=20, TOKEN_EMBED=300, CHAR_EMBED=50, NUM_FILTERS=200, KERNEL=3
// HID=256, LABELS=8, NS=6, D0=500, D1=512, BL=4096

typedef float floatx2 __attribute__((ext_vector_type(2)));
typedef short bf16x8 __attribute__((ext_vector_type(8)));
typedef float f32x4  __attribute__((ext_vector_type(4)));

__device__ __forceinline__ unsigned short f2bf(float x) {
    unsigned u = __float_as_uint(x);
    unsigned r = (u + 0x7fffu + ((u >> 16) & 1u)) >> 16;
    return (unsigned short)r;
}

// ---------------------------------------------------------------------------
// Prep: pack w_hh (both layers) to fp8 e4m3 as uint2 per (dir,k2,t):
//   .x = packed (i,f,g,o) for k=2*k2, .y = for k=2*k2+1.
// Also transpose crf_w / conv_w; zero d_out.
// ---------------------------------------------------------------------------
__global__ void prep(const float* __restrict__ wh0, const float* __restrict__ wh1,
                     const float* __restrict__ crf_w, const float* __restrict__ conv_w,
                     uint2* __restrict__ Wp0, uint2* __restrict__ Wp1,
                     float* __restrict__ crfBT, float* __restrict__ convWT,
                     float* __restrict__ outp)
{
    int idx = blockIdx.x * 256 + threadIdx.x;
    if (idx == 0) outp[0] = 0.f;
    const int NWP = 2 * 2 * 128 * 256;   // layer, dir, k2, t = 131072
    if (idx < NWP) {
        int layer = idx >> 16;
        int r     = idx & 65535;
        int dir   = r >> 15;
        int q     = r & 32767;
        int k2    = q >> 8;              // 0..127
        int t     = q & 255;
        const float* w = (layer ? wh1 : wh0) + dir * 1024 * 256;
        uint2 v;
        {
            int k = 2 * k2;
            float wi = w[(t      ) * 256 + k];
            float wf = w[(256 + t) * 256 + k];
            float wg = w[(512 + t) * 256 + k];
            float wo = w[(768 + t) * 256 + k];
            int u = __builtin_amdgcn_cvt_pk_fp8_f32(wi, wf, 0, false);
            u     = __builtin_amdgcn_cvt_pk_fp8_f32(wg, wo, u, true);
            v.x = (unsigned)u;
        }
        {
            int k = 2 * k2 + 1;
            float wi = w[(t      ) * 256 + k];
            float wf = w[(256 + t) * 256 + k];
            float wg = w[(512 + t) * 256 + k];
            float wo = w[(768 + t) * 256 + k];
            int u = __builtin_amdgcn_cvt_pk_fp8_f32(wi, wf, 0, false);
            u     = __builtin_amdgcn_cvt_pk_fp8_f32(wg, wo, u, true);
            v.y = (unsigned)u;
        }
        ((layer ? Wp1 : Wp0))[(size_t)dir * 32768 + k2 * 256 + t] = v;
        return;
    }
    idx -= NWP;
    if (idx < 48 * 512) {
        int jj = idx >> 9, d = idx & 511;
        int kL = jj / 6, n = jj % 6;
        crfBT[idx] = crf_w[(kL * 512 + d) * 6 + n];
        return;
    }
    idx -= 48 * 512;
    if (idx < 30000) {
        int f = idx % 200, ek = idx / 200;
        int e = ek / 3, kk = ek % 3;
        convWT[idx] = conv_w[(f * 50 + e) * 3 + kk];
        return;
    }
}

// ---------------------------------------------------------------------------
// Embeddings + char conv + concat -> inp (4096 x 500)
// ---------------------------------------------------------------------------
__global__ __launch_bounds__(256) void embed_conv(
    const int* __restrict__ iv, const int* __restrict__ ov, const int* __restrict__ ch,
    const float* __restrict__ emb, const float* __restrict__ ooev, const float* __restrict__ ctab,
    const float* __restrict__ convWT, const float* __restrict__ convB,
    float* __restrict__ inp)
{
    const int bl = blockIdx.x;
    const int tid = threadIdx.x;
    __shared__ float sx[50 * 20];
    const int ivv = iv[bl];
    const int ovv = ov[bl];
    const float mo = (ovv != 0) ? 1.f : 0.f;
    for (int e = tid; e < 300; e += 256)
        inp[bl * 500 + e] = emb[(size_t)ivv * 300 + e] + mo * ooev[(size_t)ovv * 300 + e];
    for (int i = tid; i < 1000; i += 256) {
        int cI = i / 50, e = i % 50;
        int id = ch[bl * 20 + cI];
        sx[e * 20 + cI] = id ? ctab[id * 50 + e] : 0.f;
    }
    __syncthreads();
    if (tid < 200) {
        float acc[22];
        float bz = convB[tid];
        #pragma unroll
        for (int o = 0; o < 22; ++o) acc[o] = bz;
        for (int e = 0; e < 50; ++e) {
            float xr[20];
            #pragma unroll
            for (int q = 0; q < 5; ++q) {
                float4 v = *(const float4*)&sx[e * 20 + q * 4];
                xr[q * 4 + 0] = v.x; xr[q * 4 + 1] = v.y;
                xr[q * 4 + 2] = v.z; xr[q * 4 + 3] = v.w;
            }
            float w0 = convWT[(e * 3 + 0) * 200 + tid];
            float w1 = convWT[(e * 3 + 1) * 200 + tid];
            float w2 = convWT[(e * 3 + 2) * 200 + tid];
            #pragma unroll
            for (int o = 0; o < 22; ++o) {
                float s = acc[o];
                if (o >= 2)            s = fmaf(xr[o - 2], w0, s);
                if (o >= 1 && o <= 20) s = fmaf(xr[o - 1], w1, s);
                if (o <= 19)           s = fmaf(xr[o],     w2, s);
                acc[o] = s;
            }
        }
        float mx = acc[0];
        #pragma unroll
        for (int o = 1; o < 22; ++o) mx = fmaxf(mx, acc[o]);
        inp[bl * 500 + 300 + tid] = 1.f / (1.f + expf(-mx));
    }
}

// ---------------------------------------------------------------------------
// MFMA bf16 GEMM (verified correct in R7/R8/R9: absmax 0.0)
// ---------------------------------------------------------------------------
__global__ __launch_bounds__(256) void gemm_mfma(
    const float* __restrict__ A, const float* __restrict__ Bm,
    const float* __restrict__ bias, float* __restrict__ C,
    int M, int N, int K)
{
    __shared__ unsigned short As[4][128][8];
    __shared__ unsigned short Bs[4][128][8];
    const int tid  = threadIdx.x;
    const int wave = tid >> 6, lane = tid & 63;
    const int quad = lane >> 4, lr = lane & 15;
    const int m0 = blockIdx.y * 128, n0 = blockIdx.x * 128;

    f32x4 acc[2][8];
    #pragma unroll
    for (int mt = 0; mt < 2; ++mt)
        #pragma unroll
        for (int nt = 0; nt < 8; ++nt) acc[mt][nt] = (f32x4){0.f, 0.f, 0.f, 0.f};

    const int ktiles = (K + 31) >> 5;
    for (int kt = 0; kt < ktiles; ++kt) {
        #pragma unroll
        for (int i = 0; i < 4; ++i) {
            int vid = tid + i * 256;
            int row = vid >> 3, kq = vid & 7;
            int kb  = kt * 32 + kq * 4;
            unsigned short ta[4], tb[4];
            const float* pa = A  + (size_t)(m0 + row) * K + kb;
            const float* pb = Bm + (size_t)(n0 + row) * K + kb;
            #pragma unroll
            for (int j = 0; j < 4; ++j) {
                ta[j] = (kb + j < K) ? f2bf(pa[j]) : (unsigned short)0;
                tb[j] = (kb + j < K) ? f2bf(pb[j]) : (unsigned short)0;
            }
            int ko = kq >> 1, jo = (kq & 1) * 4;
            *(ushort4*)&As[ko][row][jo] = make_ushort4(ta[0], ta[1], ta[2], ta[3]);
            *(ushort4*)&Bs[ko][row][jo] = make_ushort4(tb[0], tb[1], tb[2], tb[3]);
        }
        __syncthreads();
        bf16x8 bfr[8];
        #pragma unroll
        for (int nt = 0; nt < 8; ++nt)
            bfr[nt] = *(const bf16x8*)&Bs[quad][nt * 16 + lr][0];
        #pragma unroll
        for (int mt = 0; mt < 2; ++mt) {
            bf16x8 afr = *(const bf16x8*)&As[quad][wave * 32 + mt * 16 + lr][0];
            #pragma unroll
            for (int nt = 0; nt < 8; ++nt)
                acc[mt][nt] = __builtin_amdgcn_mfma_f32_16x16x32_bf16(
                    afr, bfr[nt], acc[mt][nt], 0, 0, 0);
        }
        __syncthreads();
    }
    #pragma unroll
    for (int mt = 0; mt < 2; ++mt)
        #pragma unroll
        for (int r = 0; r < 4; ++r) {
            int m = m0 + wave * 32 + mt * 16 + quad * 4 + r;
            #pragma unroll
            for (int nt = 0; nt < 8; ++nt) {
                int n = n0 + nt * 16 + lr;
                C[(size_t)m * N + n] = acc[mt][nt][r] + bias[n];
            }
        }
}

// ---------------------------------------------------------------------------
// fp32 GEMM (kept for the small emission GEMM, N=48)
// ---------------------------------------------------------------------------
__global__ __launch_bounds__(256) void gemm_bt(
    const float* __restrict__ A, const float* __restrict__ Bm,
    const float* __restrict__ bias, float* __restrict__ C,
    int M, int N, int K)
{
    __shared__ float At[16 * 128];
    __shared__ float Bt[16 * 128];
    const int tid = threadIdx.x;
    const int tx = tid & 15, ty = tid >> 4;
    const int m0 = blockIdx.y * 128, n0 = blockIdx.x * 128;
    float acc[2][2][4][4];
    #pragma unroll
    for (int a = 0; a < 2; ++a)
        #pragma unroll
        for (int b = 0; b < 2; ++b)
            #pragma unroll
            for (int i = 0; i < 4; ++i)
                #pragma unroll
                for (int j = 0; j < 4; ++j) acc[a][b][i][j] = 0.f;

    const int lr = tid >> 2;
    const int lc = (tid & 3) << 2;
    const int ktiles = (K + 15) >> 4;
    for (int kt = 0; kt < ktiles; ++kt) {
        const int k0 = kt << 4;
        #pragma unroll
        for (int half = 0; half < 2; ++half) {
            int r = lr + half * 64;
            int gk = k0 + lc;
            {
                int gm = m0 + r;
                float4 v = make_float4(0.f, 0.f, 0.f, 0.f);
                if (gm < M) {
                    const float* p = A + (size_t)gm * K + gk;
                    if (gk + 3 < K) v = *(const float4*)p;
                    else {
                        if (gk + 0 < K) v.x = p[0];
                        if (gk + 1 < K) v.y = p[1];
                        if (gk + 2 < K) v.z = p[2];
                        if (gk + 3 < K) v.w = p[3];
                    }
                }
                At[(lc + 0) * 128 + r] = v.x; At[(lc + 1) * 128 + r] = v.y;
                At[(lc + 2) * 128 + r] = v.z; At[(lc + 3) * 128 + r] = v.w;
            }
            {
                int gn = n0 + r;
                float4 v = make_float4(0.f, 0.f, 0.f, 0.f);
                if (gn < N) {
                    const float* p = Bm + (size_t)gn * K + gk;
                    if (gk + 3 < K) v = *(const float4*)p;
                    else {
                        if (gk + 0 < K) v.x = p[0];
                        if (gk + 1 < K) v.y = p[1];
                        if (gk + 2 < K) v.z = p[2];
                        if (gk + 3 < K) v.w = p[3];
                    }
                }
                Bt[(lc + 0) * 128 + r] = v.x; Bt[(lc + 1) * 128 + r] = v.y;
                Bt[(lc + 2) * 128 + r] = v.z; Bt[(lc + 3) * 128 + r] = v.w;
            }
        }
        __syncthreads();
        #pragma unroll
        for (int k = 0; k < 16; ++k) {
            float4 a0 = *(const float4*)&At[k * 128 + (ty << 2)];
            float4 a1 = *(const float4*)&At[k * 128 + 64 + (ty << 2)];
            float4 b0 = *(const float4*)&Bt[k * 128 + (tx << 2)];
            float4 b1 = *(const float4*)&Bt[k * 128 + 64 + (tx << 2)];
            float am[2][4] = {{a0.x, a0.y, a0.z, a0.w}, {a1.x, a1.y, a1.z, a1.w}};
            float bn[2][4] = {{b0.x, b0.y, b0.z, b0.w}, {b1.x, b1.y, b1.z, b1.w}};
            #pragma unroll
            for (int qa = 0; qa < 2; ++qa)
                #pragma unroll
                for (int qb = 0; qb < 2; ++qb)
                    #pragma unroll
                    for (int i = 0; i < 4; ++i)
                        #pragma unroll
                        for (int j = 0; j < 4; ++j)
                            acc[qa][qb][i][j] = fmaf(am[qa][i], bn[qb][j], acc[qa][qb][i][j]);
        }
        __syncthreads();
    }
    #pragma unroll
    for (int qa = 0; qa < 2; ++qa)
        #pragma unroll
        for (int i = 0; i < 4; ++i) {
            int m = m0 + qa * 64 + (ty << 2) + i;
            if (m >= M) continue;
            #pragma unroll
            for (int qb = 0; qb < 2; ++qb)
                #pragma unroll
                for (int j = 0; j < 4; ++j) {
                    int n = n0 + qb * 64 + (tx << 2) + j;
                    if (n < N) C[(size_t)m * N + n] = acc[qa][qb][i][j] + bias[n];
                }
        }
}

// ---------------------------------------------------------------------------
// LSTM recurrence v10: heterogeneous 512-thread split, 8 waves (2/SIMD).
//  thread (kh, t):  kh=0 -> k2 in [0,64)   all from LDS
//                   kh=1 -> k2 in [64,76) LDS + [76,104) REGISTERS (28 uint2
//                           = 56 VGPRs, small enough to avoid R7/R8 spill
//                           cliff) + [104,128) streamed (49 KB/step from L2)
// Each SIMD hosts one kh0 (VALU/LDS) and one kh1 (stream) wave -> mutual
// latency hiding (m114). Partials reduced via LDS; t-owners = kh0 threads.
// LDS: 152 KB weights + 4 KB partials + 1.5 KB hs/msk = 157.6 KB < 160.
// ---------------------------------------------------------------------------
#define KLDS 76
#define KREG 28
__global__ __launch_bounds__(512, 1) void lstm_rec(
    const float* __restrict__ xs, const uint2* __restrict__ Wp,
    const float* __restrict__ mask, float* __restrict__ out)
{
    const int tid = threadIdx.x;
    const int t   = tid & 255;
    const int kh  = tid >> 8;            // 0 or 1 (wave-uniform)
    const int b   = blockIdx.x >> 1;
    const int dir = blockIdx.x & 1;
    __shared__ uint2 wlds[KLDS * 256];   // 152 KB, groups [0,76)
    __shared__ float part[4][256];       // kh1 partial gate sums
    __shared__ float hs[256];
    __shared__ float msk[128];

    const uint2* wp = Wp + (size_t)dir * 32768;
    // fill LDS weights (both halves cooperate: 76 groups, 512 threads)
    for (int j = tid; j < KLDS * 256; j += 512) wlds[j] = wp[j];
    // kh1: one-time register weights, groups [76, 76+28)
    uint2 wreg[KREG];
    if (kh == 1) {
        #pragma unroll
        for (int j = 0; j < KREG; ++j) wreg[j] = wp[(KLDS + j) * 256 + t];
    }
    if (tid < 256) hs[tid] = 0.f;
    if (tid < 128) msk[tid] = mask[b * 128 + tid];
    __syncthreads();

    const uint2* wsp = wp + (KLDS + KREG) * 256 + t;  // streamed groups [104,128)
    float h = 0.f, c = 0.f;              // live on kh==0 (t-owners)
    for (int s = 0; s < 128; ++s) {
        const int l = dir ? (127 - s) : s;
        floatx2 aif = {0.f, 0.f}, ago = {0.f, 0.f};
        float gi = 0.f, gf = 0.f, gg2 = 0.f, go = 0.f;
        if (kh == 0) {
            const float* gx = xs + ((size_t)(b * 128 + l) * 2048 + dir * 1024 + t);
            gi = gx[0]; gf = gx[256]; gg2 = gx[512]; go = gx[768];
            #pragma unroll 4
            for (int k2 = 0; k2 < 64; ++k2) {
                uint2 w = wlds[k2 * 256 + t];
                float2 hv = *(const float2*)&hs[k2 * 2];
                floatx2 lo0 = __builtin_amdgcn_cvt_pk_f32_fp8((int)w.x, false);
                floatx2 hi0 = __builtin_amdgcn_cvt_pk_f32_fp8((int)w.x, true);
                floatx2 lo1 = __builtin_amdgcn_cvt_pk_f32_fp8((int)w.y, false);
                floatx2 hi1 = __builtin_amdgcn_cvt_pk_f32_fp8((int)w.y, true);
                floatx2 hx = {hv.x, hv.x}, hy = {hv.y, hv.y};
                aif += hx * lo0; ago += hx * hi0;
                aif += hy * lo1; ago += hy * hi1;
            }
        } else {
            // streamed tail first: loads go in flight early
            #pragma unroll 4
            for (int j = 0; j < 128 - KLDS - KREG; ++j) {
                uint2 w = wsp[j * 256];
                float2 hv = *(const float2*)&hs[(KLDS + KREG + j) * 2];
                floatx2 lo0 = __builtin_amdgcn_cvt_pk_f32_fp8((int)w.x, false);
                floatx2 hi0 = __builtin_amdgcn_cvt_pk_f32_fp8((int)w.x, true);
                floatx2 lo1 = __builtin_amdgcn_cvt_pk_f32_fp8((int)w.y, false);
                floatx2 hi1 = __builtin_amdgcn_cvt_pk_f32_fp8((int)w.y, true);
                floatx2 hx = {hv.x, hv.x}, hy = {hv.y, hv.y};
                aif += hx * lo0; ago += hx * hi0;
                aif += hy * lo1; ago += hy * hi1;
            }
            // LDS groups [64,76)
            #pragma unroll 4
            for (int j = 0; j < KLDS - 64; ++j) {
                uint2 w = wlds[(64 + j) * 256 + t];
                float2 hv = *(const float2*)&hs[(64 + j) * 2];
                floatx2 lo0 = __builtin_amdgcn_cvt_pk_f32_fp8((int)w.x, false);
                floatx2 hi0 = __builtin_amdgcn_cvt_pk_f32_fp8((int)w.x, true);
                floatx2 lo1 = __builtin_amdgcn_cvt_pk_f32_fp8((int)w.y, false);
                floatx2 hi1 = __builtin_amdgcn_cvt_pk_f32_fp8((int)w.y, true);
                floatx2 hx = {hv.x, hv.x}, hy = {hv.y, hv.y};
                aif += hx * lo0; ago += hx * hi0;
                aif += hy * lo1; ago += hy * hi1;
            }
            // register groups [76,104) - fully unrolled (constant indices)
            #pragma unroll
            for (int j = 0; j < KREG; ++j) {
                uint2 w = wreg[j];
                float2 hv = *(const float2*)&hs[(KLDS + j) * 2];
                floatx2 lo0 = __builtin_amdgcn_cvt_pk_f32_fp8((int)w.x, false);
                floatx2 hi0 = __builtin_amdgcn_cvt_pk_f32_fp8((int)w.x, true);
                floatx2 lo1 = __builtin_amdgcn_cvt_pk_f32_fp8((int)w.y, false);
                floatx2 hi1 = __builtin_amdgcn_cvt_pk_f32_fp8((int)w.y, true);
                floatx2 hx = {hv.x, hv.x}, hy = {hv.y, hv.y};
                aif += hx * lo0; ago += hx * hi0;
                aif += hy * lo1; ago += hy * hi1;
            }
            part[0][t] = aif.x; part[1][t] = aif.y;
            part[2][t] = ago.x; part[3][t] = ago.y;
        }
        __syncthreads();                 // kh1 partials written; hs reads done
        if (kh == 0) {
            float sai = aif.x + gi + part[0][t];
            float saf = aif.y + gf + part[1][t];
            float sag = ago.x + gg2 + part[2][t];
            float sao = ago.y + go + part[3][t];
            float ig = 1.f / (1.f + __expf(-sai));
            float fg = 1.f / (1.f + __expf(-saf));
            float gg = tanhf(sag);
            float og = 1.f / (1.f + __expf(-sao));
            float cn = fmaf(fg, c, ig * gg);
            float hn = og * tanhf(cn);
            float m = msk[l];
            h = m * hn + (1.f - m) * h;
            c = m * cn + (1.f - m) * c;
            hs[t] = h;
            out[(size_t)(b * 128 + l) * 512 + dir * 256 + t] = h;
        }
        __syncthreads();                 // new hs visible for next step
    }
}
#undef KLDS
#undef KREG

// ---------------------------------------------------------------------------
// CRF loss: 8 blocks (one per label k), 192 threads = (b in 0..31, j in 0..5)
// ---------------------------------------------------------------------------
__global__ __launch_bounds__(192) void crf_loss(
    const float* __restrict__ em, const float* __restrict__ trans,
    const int* __restrict__ target, const float* __restrict__ mask,
    float* __restrict__ outp)
{
    const int k = blockIdx.x;
    const int tid = threadIdx.x;
    const int b = tid & 31;
    const int j = tid >> 5;
    __shared__ float T[36];
    __shared__ float As[32][6];
    __shared__ float red[192];
    if (tid < 36) T[tid] = trans[k * 36 + tid];
    __syncthreads();
    const int* tg = target + (k * 32 + b) * 128;
    float sc = 0.f;
    for (int l = j; l < 128; l += 6) {
        int y = tg[l];
        float m = mask[b * 128 + l];
        sc += m * em[(b * 128 + l) * 48 + k * 6 + y];
        if (l > 0) sc += m * T[tg[l - 1] * 6 + y];
    }
    red[tid] = sc;
    float a = em[(b * 128) * 48 + k * 6 + j];
    As[b][j] = a;
    __syncthreads();
    for (int l = 1; l < 128; ++l) {
        float e = em[(b * 128 + l) * 48 + k * 6 + j];
        float v0 = As[b][0] + T[0 * 6 + j];
        float v1 = As[b][1] + T[1 * 6 + j];
        float v2 = As[b][2] + T[2 * 6 + j];
        float v3 = As[b][3] + T[3 * 6 + j];
        float v4 = As[b][4] + T[4 * 6 + j];
        float v5 = As[b][5] + T[5 * 6 + j];
        float mx = fmaxf(fmaxf(fmaxf(v0, v1), fmaxf(v2, v3)), fmaxf(v4, v5));
        float ssum = expf(v0 - mx) + expf(v1 - mx) + expf(v2 - mx)
                   + expf(v3 - mx) + expf(v4 - mx) + expf(v5 - mx);
        float na = mx + logf(ssum) + e;
        float m = mask[b * 128 + l];
        a = m * na + (1.f - m) * a;
        __syncthreads();
        As[b][j] = a;
        __syncthreads();
    }
    if (j == 0) {
        float v0 = As[b][0], v1 = As[b][1], v2 = As[b][2];
        float v3 = As[b][3], v4 = As[b][4], v5 = As[b][5];
        float mx = fmaxf(fmaxf(fmaxf(v0, v1), fmaxf(v2, v3)), fmaxf(v4, v5));
        float ssum = expf(v0 - mx) + expf(v1 - mx) + expf(v2 - mx)
                   + expf(v3 - mx) + expf(v4 - mx) + expf(v5 - mx);
        float logZ = mx + logf(ssum);
        float scb = red[b] + red[b + 32] + red[b + 64] + red[b + 96] + red[b + 128] + red[b + 160];
        red[b] = logZ - scb;
    }
    __syncthreads();
    if (tid == 0) {
        float tot = 0.f;
        for (int bb = 0; bb < 32; ++bb) tot += red[bb];
        atomicAdd(outp, tot * (1.f / 32.f));
    }
}

// ---------------------------------------------------------------------------
extern "C" void kernel_launch(void* const* d_in, const int* in_sizes, int n_in,
                              void* d_out, int out_size, void* d_ws, size_t ws_size,
                              hipStream_t stream)
{
    const int*   iv    = (const int*)d_in[0];
    const int*   ov    = (const int*)d_in[1];
    const int*   ch    = (const int*)d_in[2];
    const int*   tgt   = (const int*)d_in[3];
    const float* mask  = (const float*)d_in[4];
    const float* emb   = (const float*)d_in[5];
    const float* ooevT = (const float*)d_in[6];
    const float* ctab  = (const float*)d_in[7];
    const float* convW = (const float*)d_in[8];
    const float* convB = (const float*)d_in[9];
    const float* wih0  = (const float*)d_in[10];
    const float* whh0  = (const float*)d_in[11];
    const float* b0    = (const float*)d_in[12];
    const float* wih1  = (const float*)d_in[13];
    const float* whh1  = (const float*)d_in[14];
    const float* b1    = (const float*)d_in[15];
    const float* crfW  = (const float*)d_in[16];
    const float* crfB  = (const float*)d_in[17];
    const float* crfT  = (const float*)d_in[18];
    float* outp = (float*)d_out;

    char* ws = (char*)d_ws;
    size_t off = 0;
    auto alloc = [&](size_t bytes) {
        void* p = ws + off;
        off = (off + bytes + 255) & ~(size_t)255;
        return p;
    };
    float* inp    = (float*)alloc((size_t)4096 * 500 * 4);
    float* xs     = (float*)alloc((size_t)4096 * 2048 * 4);
    float* out0   = (float*)alloc((size_t)4096 * 512 * 4);
    float* out1   = (float*)alloc((size_t)4096 * 512 * 4);
    float* em     = (float*)alloc((size_t)4096 * 48 * 4);
    uint2* Wp0    = (uint2*)alloc((size_t)2 * 128 * 256 * 8);
    uint2* Wp1    = (uint2*)alloc((size_t)2 * 128 * 256 * 8);
    float* crfBT  = (float*)alloc((size_t)48 * 512 * 4);
    float* convWT = (float*)alloc((size_t)30000 * 4);

    const int prepN = 2 * 2 * 128 * 256 + 48 * 512 + 30000;
    prep<<<(prepN + 255) / 256, 256, 0, stream>>>(whh0, whh1, crfW, convW,
                                                  Wp0, Wp1, crfBT, convWT, outp);
    embed_conv<<<4096, 256, 0, stream>>>(iv, ov, ch, emb, ooevT, ctab, convWT, convB, inp);
    gemm_mfma<<<dim3(16, 32), 256, 0, stream>>>(inp, wih0, b0, xs, 4096, 2048, 500);
    lstm_rec<<<64, 512, 0, stream>>>(xs, Wp0, mask, out0);
    gemm_mfma<<<dim3(16, 32), 256, 0, stream>>>(out0, wih1, b1, xs, 4096, 2048, 512);
    lstm_rec<<<64, 512, 0, stream>>>(xs, Wp1, mask, out1);
    gemm_bt<<<dim3(1, 32), 256, 0, stream>>>(out1, crfBT, crfB, em, 4096, 48, 512);
    crf_loss<<<8, 192, 0, stream>>>(em, crfT, tgt, mask, outp);
}